// Round 6
// baseline (1759.020 us; speedup 1.0000x reference)
//
#include <hip/hip_runtime.h>
#include <math.h>

// Problem constants
#define NB  262144   // batch
#define SD  128      // STATE_DIM
#define HID 256      // HIDDEN
#define AD  8        // ACTION_DIM

typedef float v2f __attribute__((ext_vector_type(2)));

// d_ws layout (floats)
#define W1T_OFF 0                       // [SD][HID]   W1T[k*HID+j] = W1[j*SD+k]
#define W2T_OFF (SD*HID)                // [HID][HID]  32768
#define W3P_OFF (W2T_OFF + HID*HID)     // [HID][AD] float2 pairs (u,s): 98304, 4096 floats
#define B1_OFF  (W3P_OFF + HID*2*AD)    // 102400
#define B2_OFF  (B1_OFF + HID)          // 102656
#define B3P_OFF (B2_OFF + HID)          // 102912, [AD] float2 pairs
#define WS_FLOATS (B3P_OFF + 2*AD)      // 102928 floats = 411,712 bytes

__global__ __launch_bounds__(256) void prep_weights(
    const float* __restrict__ W1, const float* __restrict__ b1,
    const float* __restrict__ W2, const float* __restrict__ b2,
    const float* __restrict__ W3, const float* __restrict__ b3,
    float* __restrict__ ws) {
  int stride = gridDim.x * blockDim.x;
  for (int i = blockIdx.x * blockDim.x + threadIdx.x; i < WS_FLOATS; i += stride) {
    float v;
    if (i < W2T_OFF) {                       // W1T
      int k = i >> 8, j = i & 255;
      v = W1[j * SD + k];
    } else if (i < W3P_OFF) {                // W2T
      int t = i - W2T_OFF;
      int k = t >> 8, j = t & 255;
      v = W2[j * HID + k];
    } else if (i < B1_OFF) {                 // W3P[k][a] = (W3[a][k], W3[a+8][k])
      int t = i - W3P_OFF;
      int k = t >> 4, a = (t >> 1) & 7, h = t & 1;
      v = W3[(a + 8 * h) * HID + k];
    } else if (i < B2_OFF) {
      v = b1[i - B1_OFF];
    } else if (i < B3P_OFF) {
      v = b2[i - B2_OFF];
    } else {                                 // B3P[a] = (b3[a], b3[a+8])
      int t = i - B3P_OFF;
      v = b3[(t >> 1) + 8 * (t & 1)];
    }
    ws[i] = v;
  }
}

// R5 post-mortem: VALU work is near-minimal (busy time ~= FMA floor at the
// sustained clock) but 40% of cycles stall. Causes: layer-1 x fetched with
// wave-uniform GLOBAL loads (HBM-miss ~900 cyc in the dependent path; FETCH
// 71->137 MB proves it), and W loads (L2 ~200-300 cyc) with no lookahead
// (VGPR=52: compiler kept none). Fixes here:
//   * x is staged coalesced -> wave-private LDS rows at kernel start, then
//     layer 1 reads uniform ds_read_b128 broadcasts (like layer 2 already does).
//     DS ops are in-order per wave, so the later h1 overwrite of the same rows
//     needs no barrier.
//   * W is explicitly double-buffered: next k-chunk's 4 float4 loads issue
//     before the 256-cycle FMA block of the current chunk.
//   * eps is loaded at kernel start (coalesced), not at the end.
__global__ __launch_bounds__(256, 4) void actor_fused(
    const float* __restrict__ state, const float* __restrict__ eps,
    const float* __restrict__ ws, int* __restrict__ out) {
  __shared__ float s_h[32][264];   // 33,792 B -> 4 blocks/CU; stride 264: 16B-aligned

  const int tid  = threadIdx.x;
  const int lane = tid & 63;
  const int wvu  = __builtin_amdgcn_readfirstlane(tid >> 6);  // provably uniform
  const long wrow = (long)blockIdx.x * 32 + wvu * 8;          // wave's first row

  const float4* __restrict__ W1T4 = (const float4*)(ws + W1T_OFF);  // [SD][64]
  const float4* __restrict__ W2T4 = (const float4*)(ws + W2T_OFF);  // [HID][64]
  const v2f*    __restrict__ W3P  = (const v2f*)(ws + W3P_OFF);     // [HID][8]

  // ---- early eps load: out index for this lane is wrow*8 + lane (coalesced)
  const float epsv = eps[wrow * AD + lane];

  // ---- stage x coalesced -> wave-private LDS rows, cols 0..127
  #pragma unroll
  for (int r = 0; r < 8; ++r) {
    v2f xr = *(const v2f*)(state + (wrow + r) * SD + 2 * lane);
    *(v2f*)&s_h[wvu * 8 + r][2 * lane] = xr;
  }
  // no barrier: rows are wave-private; DS pipe is in-order per wave

  // ---- layer 1: h1 = relu(x @ W1^T + b1), K = 128
  float acc[8][4];
  #pragma unroll
  for (int r = 0; r < 8; ++r)
    #pragma unroll
    for (int c = 0; c < 4; ++c) acc[r][c] = 0.0f;

  {
    float4 w[4], wn[4];
    #pragma unroll
    for (int j = 0; j < 4; ++j) w[j] = W1T4[j * 64 + lane];
    #pragma unroll 2
    for (int k0 = 0; k0 < SD; k0 += 4) {
      const int kn = (k0 + 4) & (SD - 1);               // wraps to 0 on last iter
      #pragma unroll
      for (int j = 0; j < 4; ++j) wn[j] = W1T4[(kn + j) * 64 + lane];  // prefetch
      float4 xv[8];
      #pragma unroll
      for (int r = 0; r < 8; ++r)                        // uniform LDS broadcast
        xv[r] = *(const float4*)&s_h[wvu * 8 + r][k0];
      #pragma unroll
      for (int j = 0; j < 4; ++j) {
        #pragma unroll
        for (int r = 0; r < 8; ++r) {
          float x = (j == 0) ? xv[r].x : (j == 1) ? xv[r].y
                  : (j == 2) ? xv[r].z : xv[r].w;
          acc[r][0] = fmaf(x, w[j].x, acc[r][0]);
          acc[r][1] = fmaf(x, w[j].y, acc[r][1]);
          acc[r][2] = fmaf(x, w[j].z, acc[r][2]);
          acc[r][3] = fmaf(x, w[j].w, acc[r][3]);
        }
      }
      #pragma unroll
      for (int j = 0; j < 4; ++j) w[j] = wn[j];
    }
  }

  // bias + relu -> h1 into the same wave-private LDS rows (x fully consumed)
  {
    float4 bb = ((const float4*)(ws + B1_OFF))[lane];
    #pragma unroll
    for (int r = 0; r < 8; ++r) {
      float4 hv;
      hv.x = acc[r][0] + bb.x; hv.y = acc[r][1] + bb.y;
      hv.z = acc[r][2] + bb.z; hv.w = acc[r][3] + bb.w;
      hv.x = hv.x > 0.0f ? hv.x : 0.0f;
      hv.y = hv.y > 0.0f ? hv.y : 0.0f;
      hv.z = hv.z > 0.0f ? hv.z : 0.0f;
      hv.w = hv.w > 0.0f ? hv.w : 0.0f;
      *(float4*)&s_h[wvu * 8 + r][4 * lane] = hv;
    }
  }

  // ---- layer 2: h2 = relu(h1 @ W2^T + b2), K = 256
  #pragma unroll
  for (int r = 0; r < 8; ++r)
    #pragma unroll
    for (int c = 0; c < 4; ++c) acc[r][c] = 0.0f;

  {
    float4 w[4], wn[4];
    #pragma unroll
    for (int j = 0; j < 4; ++j) w[j] = W2T4[j * 64 + lane];
    #pragma unroll 2
    for (int k0 = 0; k0 < HID; k0 += 4) {
      const int kn = (k0 + 4) & (HID - 1);
      #pragma unroll
      for (int j = 0; j < 4; ++j) wn[j] = W2T4[(kn + j) * 64 + lane];  // prefetch
      float4 xv[8];
      #pragma unroll
      for (int r = 0; r < 8; ++r)                        // uniform LDS broadcast
        xv[r] = *(const float4*)&s_h[wvu * 8 + r][k0];
      #pragma unroll
      for (int j = 0; j < 4; ++j) {
        #pragma unroll
        for (int r = 0; r < 8; ++r) {
          float x = (j == 0) ? xv[r].x : (j == 1) ? xv[r].y
                  : (j == 2) ? xv[r].z : xv[r].w;
          acc[r][0] = fmaf(x, w[j].x, acc[r][0]);
          acc[r][1] = fmaf(x, w[j].y, acc[r][1]);
          acc[r][2] = fmaf(x, w[j].z, acc[r][2]);
          acc[r][3] = fmaf(x, w[j].w, acc[r][3]);
        }
      }
      #pragma unroll
      for (int j = 0; j < 4; ++j) w[j] = wn[j];
    }
  }

  // bias + relu -> h2 into the same LDS rows (all h1 reads done, in-order DS)
  {
    float4 bb = ((const float4*)(ws + B2_OFF))[lane];
    #pragma unroll
    for (int r = 0; r < 8; ++r) {
      float4 hv;
      hv.x = acc[r][0] + bb.x; hv.y = acc[r][1] + bb.y;
      hv.z = acc[r][2] + bb.z; hv.w = acc[r][3] + bb.w;
      hv.x = hv.x > 0.0f ? hv.x : 0.0f;
      hv.y = hv.y > 0.0f ? hv.y : 0.0f;
      hv.z = hv.z > 0.0f ? hv.z : 0.0f;
      hv.w = hv.w > 0.0f ? hv.w : 0.0f;
      *(float4*)&s_h[wvu * 8 + r][4 * lane] = hv;
    }
  }

  // ---- layer 3 (K=256, N=16) + epilogue. Lane -> (row = lane>>3, action = lane&7),
  // both u and s chains serial k-ascending (matches sgemm).
  {
    const int r3 = lane >> 3;
    const int a  = lane & 7;
    const float* __restrict__ h2row = &s_h[wvu * 8 + r3][0];
    float accu = 0.0f, accs = 0.0f;
    #pragma unroll 2
    for (int k0 = 0; k0 < HID; k0 += 4) {
      v2f ha = *(const v2f*)(h2row + k0);         // 8-lane broadcast reads
      v2f hb = *(const v2f*)(h2row + k0 + 2);
      v2f wp0 = W3P[(k0 + 0) * 8 + a];
      v2f wp1 = W3P[(k0 + 1) * 8 + a];
      v2f wp2 = W3P[(k0 + 2) * 8 + a];
      v2f wp3 = W3P[(k0 + 3) * 8 + a];
      accu = fmaf(ha.x, wp0.x, accu); accs = fmaf(ha.x, wp0.y, accs);
      accu = fmaf(ha.y, wp1.x, accu); accs = fmaf(ha.y, wp1.y, accs);
      accu = fmaf(hb.x, wp2.x, accu); accs = fmaf(hb.x, wp2.y, accs);
      accu = fmaf(hb.y, wp3.x, accu); accs = fmaf(hb.y, wp3.y, accs);
    }
    v2f b3p = ((const v2f*)(ws + B3P_OFF))[a];
    float nu = accu + b3p.x;
    float ns = accs + b3p.y;

    long grow = wrow + r3;
    float sa = fabsf(ns);
    float t  = __fmul_rn(sa, epsv);               // separately-rounded mul
    float z  = __fadd_rn(nu, t);                  // separately-rounded add
    float e  = (float)exp(-(double)z);            // correctly-rounded expf near boundary
    float d  = __fadd_rn(1.0f, e);
    float act = 1.0f / d;
    float q  = act * 8.0f;                        // exact
    float wq = __fadd_rn(q, 1.0f);
    out[grow * AD + a] = (int)wq;                 // truncation, as astype(int32)
  }
}

extern "C" void kernel_launch(void* const* d_in, const int* in_sizes, int n_in,
                              void* d_out, int out_size, void* d_ws, size_t ws_size,
                              hipStream_t stream) {
  const float* state = (const float*)d_in[0];
  const float* W1    = (const float*)d_in[1];
  const float* b1    = (const float*)d_in[2];
  const float* W2    = (const float*)d_in[3];
  const float* b2    = (const float*)d_in[4];
  const float* W3    = (const float*)d_in[5];
  const float* b3    = (const float*)d_in[6];
  const float* eps   = (const float*)d_in[7];
  int*   out = (int*)d_out;
  float* ws  = (float*)d_ws;   // 411,712 bytes; rebuilt every launch

  hipLaunchKernelGGL(prep_weights, dim3(128), dim3(256), 0, stream,
                     W1, b1, W2, b2, W3, b3, ws);
  hipLaunchKernelGGL(actor_fused, dim3(NB / 32), dim3(256), 0, stream,
                     state, eps, ws, out);
}

// Round 7
// 894.452 us; speedup vs baseline: 1.9666x; 1.9666x over previous
//
#include <hip/hip_runtime.h>
#include <math.h>

// Problem constants
#define NB  262144   // batch
#define SD  128      // STATE_DIM
#define HID 256      // HIDDEN
#define AD  8        // ACTION_DIM

typedef float v2f __attribute__((ext_vector_type(2)));

// d_ws layout (floats)
#define W1T_OFF 0                       // [SD][HID]   W1T[k*HID+j] = W1[j*SD+k]
#define W2T_OFF (SD*HID)                // [HID][HID]  32768
#define W3P_OFF (W2T_OFF + HID*HID)     // [HID][AD] float2 pairs (u,s): 98304, 4096 floats
#define B1_OFF  (W3P_OFF + HID*2*AD)    // 102400
#define B2_OFF  (B1_OFF + HID)          // 102656
#define B3P_OFF (B2_OFF + HID)          // 102912, [AD] float2 pairs
#define WS_FLOATS (B3P_OFF + 2*AD)      // 102928 floats = 411,712 bytes

__global__ __launch_bounds__(256) void prep_weights(
    const float* __restrict__ W1, const float* __restrict__ b1,
    const float* __restrict__ W2, const float* __restrict__ b2,
    const float* __restrict__ W3, const float* __restrict__ b3,
    float* __restrict__ ws) {
  int stride = gridDim.x * blockDim.x;
  for (int i = blockIdx.x * blockDim.x + threadIdx.x; i < WS_FLOATS; i += stride) {
    float v;
    if (i < W2T_OFF) {                       // W1T
      int k = i >> 8, j = i & 255;
      v = W1[j * SD + k];
    } else if (i < W3P_OFF) {                // W2T
      int t = i - W2T_OFF;
      int k = t >> 8, j = t & 255;
      v = W2[j * HID + k];
    } else if (i < B1_OFF) {                 // W3P[k][a] = (W3[a][k], W3[a+8][k])
      int t = i - W3P_OFF;
      int k = t >> 4, a = (t >> 1) & 7, h = t & 1;
      v = W3[(a + 8 * h) * HID + k];
    } else if (i < B2_OFF) {
      v = b1[i - B1_OFF];
    } else if (i < B3P_OFF) {
      v = b2[i - B2_OFF];
    } else {                                 // B3P[a] = (b3[a], b3[a+8])
      int t = i - B3P_OFF;
      v = b3[(t >> 1) + 8 * (t & 1)];
    }
    ws[i] = v;
  }
}

// R6 post-mortem: explicit W double-buffer + __launch_bounds__(256,4) (VGPR
// cap 128) => per-iteration scratch spills (WRITE_SIZE 8->78 MB, VALUBusy 28%).
// R7 = R5 structure + only the diagnosed fixes, no register-pressure risk:
//   * x staged coalesced -> wave-private LDS rows once at kernel start
//     (R5 read x with wave-uniform GLOBAL loads; state lines are cold in HBM,
//      ~900 cyc each, 8 in the dependent path per chunk => 40% stall).
//     Layer 1 then reads uniform ds_read_b128 broadcasts like layer 2.
//   * eps loaded early (coalesced), consumed in the epilogue.
//   * __launch_bounds__(256,3), no manual prefetch buffers.
// DS ops from one wave execute in order, so overwriting x-rows with h1 (and
// h1 with h2) needs no barrier — rows are wave-private (validated R5/R6,
// absmax 0.0).
__global__ __launch_bounds__(256, 3) void actor_fused(
    const float* __restrict__ state, const float* __restrict__ eps,
    const float* __restrict__ ws, int* __restrict__ out) {
  __shared__ float s_h[32][264];   // 33,792 B -> 4 blocks/CU; 264: 16B-aligned,
                                   // 8-bank row skew (2-way on layer-3 reads = free)

  const int tid  = threadIdx.x;
  const int lane = tid & 63;
  const int wvu  = __builtin_amdgcn_readfirstlane(tid >> 6);  // provably uniform
  const long wrow = (long)blockIdx.x * 32 + wvu * 8;          // wave's first row

  const float4* __restrict__ W1T4 = (const float4*)(ws + W1T_OFF);  // [SD][64]
  const float4* __restrict__ W2T4 = (const float4*)(ws + W2T_OFF);  // [HID][64]
  const v2f*    __restrict__ W3P  = (const v2f*)(ws + W3P_OFF);     // [HID][8]

  // ---- early eps load: this lane's epilogue element is (wrow*8 + lane), coalesced
  const float epsv = eps[wrow * AD + lane];

  // ---- stage x coalesced -> wave-private LDS rows, cols 0..127
  #pragma unroll
  for (int r = 0; r < 8; ++r) {
    v2f xr = *(const v2f*)(state + (wrow + r) * SD + 2 * lane);
    *(v2f*)&s_h[wvu * 8 + r][2 * lane] = xr;
  }
  // no barrier: rows are wave-private; DS pipe is in-order per wave

  // ---- layer 1: h1 = relu(x @ W1^T + b1), K = 128
  float acc[8][4];
  #pragma unroll
  for (int r = 0; r < 8; ++r)
    #pragma unroll
    for (int c = 0; c < 4; ++c) acc[r][c] = 0.0f;

  #pragma unroll 2
  for (int k0 = 0; k0 < SD; k0 += 4) {
    float4 w[4];
    #pragma unroll
    for (int j = 0; j < 4; ++j) w[j] = W1T4[(k0 + j) * 64 + lane];
    float4 xv[8];
    #pragma unroll
    for (int r = 0; r < 8; ++r)                        // uniform LDS broadcast
      xv[r] = *(const float4*)&s_h[wvu * 8 + r][k0];
    #pragma unroll
    for (int j = 0; j < 4; ++j) {
      #pragma unroll
      for (int r = 0; r < 8; ++r) {
        float x = (j == 0) ? xv[r].x : (j == 1) ? xv[r].y
                : (j == 2) ? xv[r].z : xv[r].w;
        acc[r][0] = fmaf(x, w[j].x, acc[r][0]);
        acc[r][1] = fmaf(x, w[j].y, acc[r][1]);
        acc[r][2] = fmaf(x, w[j].z, acc[r][2]);
        acc[r][3] = fmaf(x, w[j].w, acc[r][3]);
      }
    }
  }

  // bias + relu -> h1 into the same wave-private LDS rows (x fully consumed)
  {
    float4 bb = ((const float4*)(ws + B1_OFF))[lane];
    #pragma unroll
    for (int r = 0; r < 8; ++r) {
      float4 hv;
      hv.x = acc[r][0] + bb.x; hv.y = acc[r][1] + bb.y;
      hv.z = acc[r][2] + bb.z; hv.w = acc[r][3] + bb.w;
      hv.x = hv.x > 0.0f ? hv.x : 0.0f;
      hv.y = hv.y > 0.0f ? hv.y : 0.0f;
      hv.z = hv.z > 0.0f ? hv.z : 0.0f;
      hv.w = hv.w > 0.0f ? hv.w : 0.0f;
      *(float4*)&s_h[wvu * 8 + r][4 * lane] = hv;
    }
  }

  // ---- layer 2: h2 = relu(h1 @ W2^T + b2), K = 256
  #pragma unroll
  for (int r = 0; r < 8; ++r)
    #pragma unroll
    for (int c = 0; c < 4; ++c) acc[r][c] = 0.0f;

  #pragma unroll 2
  for (int k0 = 0; k0 < HID; k0 += 4) {
    float4 w[4];
    #pragma unroll
    for (int j = 0; j < 4; ++j) w[j] = W2T4[(k0 + j) * 64 + lane];
    float4 xv[8];
    #pragma unroll
    for (int r = 0; r < 8; ++r)                        // uniform LDS broadcast
      xv[r] = *(const float4*)&s_h[wvu * 8 + r][k0];
    #pragma unroll
    for (int j = 0; j < 4; ++j) {
      #pragma unroll
      for (int r = 0; r < 8; ++r) {
        float x = (j == 0) ? xv[r].x : (j == 1) ? xv[r].y
                : (j == 2) ? xv[r].z : xv[r].w;
        acc[r][0] = fmaf(x, w[j].x, acc[r][0]);
        acc[r][1] = fmaf(x, w[j].y, acc[r][1]);
        acc[r][2] = fmaf(x, w[j].z, acc[r][2]);
        acc[r][3] = fmaf(x, w[j].w, acc[r][3]);
      }
    }
  }

  // bias + relu -> h2 into the same LDS rows (all h1 reads done, in-order DS)
  {
    float4 bb = ((const float4*)(ws + B2_OFF))[lane];
    #pragma unroll
    for (int r = 0; r < 8; ++r) {
      float4 hv;
      hv.x = acc[r][0] + bb.x; hv.y = acc[r][1] + bb.y;
      hv.z = acc[r][2] + bb.z; hv.w = acc[r][3] + bb.w;
      hv.x = hv.x > 0.0f ? hv.x : 0.0f;
      hv.y = hv.y > 0.0f ? hv.y : 0.0f;
      hv.z = hv.z > 0.0f ? hv.z : 0.0f;
      hv.w = hv.w > 0.0f ? hv.w : 0.0f;
      *(float4*)&s_h[wvu * 8 + r][4 * lane] = hv;
    }
  }

  // ---- layer 3 (K=256, N=16) + epilogue. Lane -> (row = lane>>3, action = lane&7),
  // both u and s chains serial k-ascending (matches sgemm).
  {
    const int r3 = lane >> 3;
    const int a  = lane & 7;
    const float* __restrict__ h2row = &s_h[wvu * 8 + r3][0];
    float accu = 0.0f, accs = 0.0f;
    #pragma unroll 2
    for (int k0 = 0; k0 < HID; k0 += 4) {
      v2f ha = *(const v2f*)(h2row + k0);         // 8-lane broadcast reads
      v2f hb = *(const v2f*)(h2row + k0 + 2);
      v2f wp0 = W3P[(k0 + 0) * 8 + a];
      v2f wp1 = W3P[(k0 + 1) * 8 + a];
      v2f wp2 = W3P[(k0 + 2) * 8 + a];
      v2f wp3 = W3P[(k0 + 3) * 8 + a];
      accu = fmaf(ha.x, wp0.x, accu); accs = fmaf(ha.x, wp0.y, accs);
      accu = fmaf(ha.y, wp1.x, accu); accs = fmaf(ha.y, wp1.y, accs);
      accu = fmaf(hb.x, wp2.x, accu); accs = fmaf(hb.x, wp2.y, accs);
      accu = fmaf(hb.y, wp3.x, accu); accs = fmaf(hb.y, wp3.y, accs);
    }
    v2f b3p = ((const v2f*)(ws + B3P_OFF))[a];
    float nu = accu + b3p.x;
    float ns = accs + b3p.y;

    long grow = wrow + r3;
    float sa = fabsf(ns);
    float t  = __fmul_rn(sa, epsv);               // separately-rounded mul
    float z  = __fadd_rn(nu, t);                  // separately-rounded add
    float e  = (float)exp(-(double)z);            // correctly-rounded expf near boundary
    float d  = __fadd_rn(1.0f, e);
    float act = 1.0f / d;
    float q  = act * 8.0f;                        // exact
    float wq = __fadd_rn(q, 1.0f);
    out[grow * AD + a] = (int)wq;                 // truncation, as astype(int32)
  }
}

extern "C" void kernel_launch(void* const* d_in, const int* in_sizes, int n_in,
                              void* d_out, int out_size, void* d_ws, size_t ws_size,
                              hipStream_t stream) {
  const float* state = (const float*)d_in[0];
  const float* W1    = (const float*)d_in[1];
  const float* b1    = (const float*)d_in[2];
  const float* W2    = (const float*)d_in[3];
  const float* b2    = (const float*)d_in[4];
  const float* W3    = (const float*)d_in[5];
  const float* b3    = (const float*)d_in[6];
  const float* eps   = (const float*)d_in[7];
  int*   out = (int*)d_out;
  float* ws  = (float*)d_ws;   // 411,712 bytes; rebuilt every launch

  hipLaunchKernelGGL(prep_weights, dim3(128), dim3(256), 0, stream,
                     W1, b1, W2, b2, W3, b3, ws);
  hipLaunchKernelGGL(actor_fused, dim3(NB / 32), dim3(256), 0, stream,
                     state, eps, ws, out);
}